// Round 9
// baseline (116.379 us; speedup 1.0000x reference)
//
#include <hip/hip_runtime.h>
#include <hip/hip_bf16.h>

// C[1024,16384] = l2norm_rows(inputs[1024,2048]) @ features[16384,2048]^T / 0.05
// Round 9: whole-tile barrier intervals in the GEMM. 2 barriers per K-tile
// (was 16): barrier A -> [24 ds_read + 64 MFMA, compiler-pipelined] ->
// lgkmcnt(0) -> barrier B -> stage T+2 -> vmcnt(8). De-serializes the LDS
// pipe (2304 cy/tile) from the MFMA pipe (2483 cy/tile).

typedef short bf16x8 __attribute__((ext_vector_type(8)));
typedef float f32x4  __attribute__((ext_vector_type(4)));

#define D_K   2048
#define N_N   16384
#define M_M   1024
#define TEMP_INV 20.0f

__device__ __forceinline__ unsigned short f2bf(float f) {
    unsigned u = __builtin_bit_cast(unsigned, f);
    u += 0x7FFFu + ((u >> 16) & 1u);   // round-to-nearest-even (finite data)
    return (unsigned short)(u >> 16);
}

#define GLOAD16(g, l) __builtin_amdgcn_global_load_lds(                        \
    (const __attribute__((address_space(1))) unsigned int*)(g),                \
    (__attribute__((address_space(3))) unsigned int*)(l), 16, 0, 0)

// ---------------- pass 1: prep = anorm (blocks 0..1023) + bconv (rest) ----
__global__ __launch_bounds__(256) void prep_kernel(const float* __restrict__ x,
                                                   const float* __restrict__ B,
                                                   unsigned short* __restrict__ abf,
                                                   unsigned short* __restrict__ bbf) {
    int t = threadIdx.x;
    if (blockIdx.x < M_M) {
        int row = blockIdx.x;
        const float4* xr = reinterpret_cast<const float4*>(x + (size_t)row * D_K);
        float4 a = xr[t * 2];
        float4 b = xr[t * 2 + 1];
        float s = a.x*a.x + a.y*a.y + a.z*a.z + a.w*a.w
                + b.x*b.x + b.y*b.y + b.z*b.z + b.w*b.w;
        #pragma unroll
        for (int off = 32; off > 0; off >>= 1) s += __shfl_down(s, off);
        __shared__ float ps[4];
        __shared__ float sbc;
        if ((t & 63) == 0) ps[t >> 6] = s;
        __syncthreads();
        if (t == 0) {
            float tot = ps[0] + ps[1] + ps[2] + ps[3];
            sbc = 1.0f / fmaxf(sqrtf(tot), 1e-12f);
        }
        __syncthreads();
        float rs = sbc;
        bf16x8 v;
        v[0] = (short)f2bf(a.x * rs); v[1] = (short)f2bf(a.y * rs);
        v[2] = (short)f2bf(a.z * rs); v[3] = (short)f2bf(a.w * rs);
        v[4] = (short)f2bf(b.x * rs); v[5] = (short)f2bf(b.y * rs);
        v[6] = (short)f2bf(b.z * rs); v[7] = (short)f2bf(b.w * rs);
        *reinterpret_cast<bf16x8*>(abf + (size_t)row * D_K + t * 8) = v;
    } else {
        const size_t nv = (size_t)N_N * D_K / 8;
        size_t stride = (size_t)(gridDim.x - M_M) * blockDim.x;
        for (size_t v = (size_t)(blockIdx.x - M_M) * blockDim.x + t; v < nv; v += stride) {
            const float4* p = reinterpret_cast<const float4*>(B) + v * 2;
            float4 a = p[0], b = p[1];
            bf16x8 o;
            o[0] = (short)f2bf(a.x); o[1] = (short)f2bf(a.y);
            o[2] = (short)f2bf(a.z); o[3] = (short)f2bf(a.w);
            o[4] = (short)f2bf(b.x); o[5] = (short)f2bf(b.y);
            o[6] = (short)f2bf(b.z); o[7] = (short)f2bf(b.w);
            reinterpret_cast<bf16x8*>(bbf)[v] = o;
        }
    }
}

// ---------------- pass 2: 256x256 GEMM, whole-tile barrier intervals ------
// 512 threads = 8 waves (2M x 4N). LDS 128 KiB = buf[2] x {A 32K, B 32K}.
// Per tile T (buf b = T&1):
//   barrier A  (staging for T certified by vmcnt(8) at T-1 tail)
//   24 ds_read_b128 + 64 MFMA  -- NO pinning; compiler emits counted lgkmcnt
//   lgkmcnt(0); barrier B      -- all waves done reading buf b
//   stage T+2 -> buf b (8 GLOAD16)   -- WAR-safe
//   vmcnt(8)                   -- retires staging for T+1 (issued T-1 tail)
// Ledger: stages for T issued at T-2 tail; retired T-1 tail; read tile T.
__global__ __launch_bounds__(512, 2) void gemm8_kernel(const unsigned short* __restrict__ Abf,
                                                       const unsigned short* __restrict__ Bbf,
                                                       float* __restrict__ C) {
    __shared__ __align__(16) unsigned short lds[65536];   // 128 KiB

    // 256 wgs = 4 Mtiles x 64 Ntiles; bijective XCD swizzle (256 % 8 == 0).
    int bid = blockIdx.x;
    int wg  = (bid & 7) * 32 + (bid >> 3);
    int tm  = wg & 3, tn = wg >> 2;
    int m_blk = tm * 256, n_blk = tn * 256;

    int t = threadIdx.x, lane = t & 63, w = t >> 6;
    int wm = w >> 2, wn = w & 3;                     // 2 x 4 wave grid

    // ds_read lane constants: slot = chunk ^ ((row>>1)&3)
    int l15  = lane & 15;
    int slot = ((lane >> 4) ^ ((l15 >> 1) & 3)) * 16;     // byte slot offset
    int aoff = (wm * 128 + l15) * 64 + slot;              // A region byte off
    int boff = (wn * 64  + l15) * 64 + slot;              // B region byte off

    // stage source pointers (pre-swizzled global chunk per rule #21)
    const unsigned short* gA[2];
    const unsigned short* gB[2];
    int sdst[2];
    #pragma unroll
    for (int pass = 0; pass < 2; ++pass) {
        int r = pass * 128 + (t >> 2);
        int csrc = (t & 3) ^ ((r >> 1) & 3);
        gA[pass] = Abf + (size_t)(m_blk + r) * D_K + csrc * 8;
        gB[pass] = Bbf + (size_t)(n_blk + r) * D_K + csrc * 8;
        sdst[pass] = pass * 8192 + w * 1024;   // wave-uniform LDS dest base
    }

    // stage all 4 regions (A s0/s1, B s0/s1) of K-tile kt into buffer b
    auto stageTile = [&](int b, int ktile) {
        int kt = ktile < 32 ? ktile : 31;              // tail clamp (dead regions)
        #pragma unroll
        for (int s = 0; s < 2; ++s) {
            int koff = kt * 64 + s * 32;
            GLOAD16(gA[0] + koff, (char*)lds + b * 65536 + s * 16384 + sdst[0]);
            GLOAD16(gA[1] + koff, (char*)lds + b * 65536 + s * 16384 + sdst[1]);
            GLOAD16(gB[0] + koff, (char*)lds + b * 65536 + 32768 + s * 16384 + sdst[0]);
            GLOAD16(gB[1] + koff, (char*)lds + b * 65536 + 32768 + s * 16384 + sdst[1]);
        }
    };

    f32x4 acc[8][4] = {};

    // prologue: stage T0 -> buf0, T1 -> buf1; vmcnt(8) retires T0
    stageTile(0, 0);
    stageTile(1, 1);
    asm volatile("s_waitcnt vmcnt(8)" ::: "memory");
    asm volatile("s_barrier" ::: "memory");            // barrier A of tile 0

    for (int T = 0; T < 32; ++T) {
        int b = T & 1;
        char* base = (char*)lds + b * 65536;

        // whole-tile compute: s0 reads, s1 reads, s0 MFMAs, s1 MFMAs.
        // Compiler interleaves with counted lgkmcnt (s1 drain hides under s0 MFMA).
        bf16x8 a0[8], b0[4], a1[8], b1[4];
        #pragma unroll
        for (int ff = 0; ff < 8; ++ff)
            a0[ff] = *reinterpret_cast<const bf16x8*>(
                base + aoff + (((ff >> 2) * 64 + (ff & 3) * 16) * 64));
        #pragma unroll
        for (int n = 0; n < 4; ++n)
            b0[n] = *reinterpret_cast<const bf16x8*>(
                base + 32768 + boff + n * 1024);
        #pragma unroll
        for (int ff = 0; ff < 8; ++ff)
            a1[ff] = *reinterpret_cast<const bf16x8*>(
                base + 16384 + aoff + (((ff >> 2) * 64 + (ff & 3) * 16) * 64));
        #pragma unroll
        for (int n = 0; n < 4; ++n)
            b1[n] = *reinterpret_cast<const bf16x8*>(
                base + 32768 + 16384 + boff + n * 1024);

        #pragma unroll
        for (int ff = 0; ff < 8; ++ff)
            #pragma unroll
            for (int n = 0; n < 4; ++n)
                acc[ff][n] = __builtin_amdgcn_mfma_f32_16x16x32_bf16(
                    a0[ff], b0[n], acc[ff][n], 0, 0, 0);
        #pragma unroll
        for (int ff = 0; ff < 8; ++ff)
            #pragma unroll
            for (int n = 0; n < 4; ++n)
                acc[ff][n] = __builtin_amdgcn_mfma_f32_16x16x32_bf16(
                    a1[ff], b1[n], acc[ff][n], 0, 0, 0);

        asm volatile("s_waitcnt lgkmcnt(0)" ::: "memory");
        __builtin_amdgcn_sched_barrier(0);
        asm volatile("s_barrier" ::: "memory");        // barrier B: reads done
        stageTile(b, T + 2);                           // WAR-safe overwrite
        asm volatile("s_waitcnt vmcnt(8)" ::: "memory"); // retire T+1 staging
        asm volatile("s_barrier" ::: "memory");        // barrier A of T+1
    }

    // epilogue: C/D layout col=lane&15, row=(lane>>4)*4+j [m89-verified]
    #pragma unroll
    for (int f = 0; f < 8; ++f) {
        int r = m_blk + wm * 128 + (f >> 2) * 64 + (f & 3) * 16 + (lane >> 4) * 4;
        #pragma unroll
        for (int j = 0; j < 4; ++j) {
            float* cp = C + (size_t)(r + j) * N_N + n_blk + wn * 64 + (lane & 15);
            #pragma unroll
            for (int n = 0; n < 4; ++n)
                cp[n * 16] = acc[f][n][j] * TEMP_INV;
        }
    }
}

// ================= fallback (round-1 fused fp32-staged kernel) ============
__global__ __launch_bounds__(256) void rnorm_kernel(const float* __restrict__ x,
                                                    float* __restrict__ rn) {
    int row = blockIdx.x;
    const float4* xr = reinterpret_cast<const float4*>(x + (size_t)row * D_K);
    int t = threadIdx.x;
    float4 a = xr[t];
    float4 b = xr[t + 256];
    float s = a.x*a.x + a.y*a.y + a.z*a.z + a.w*a.w
            + b.x*b.x + b.y*b.y + b.z*b.z + b.w*b.w;
    #pragma unroll
    for (int off = 32; off > 0; off >>= 1) s += __shfl_down(s, off);
    __shared__ float ps[4];
    int wave = t >> 6, lane = t & 63;
    if (lane == 0) ps[wave] = s;
    __syncthreads();
    if (t == 0) {
        float tot = ps[0] + ps[1] + ps[2] + ps[3];
        rn[row] = 1.0f / fmaxf(sqrtf(tot), 1e-12f);
    }
}

__global__ __launch_bounds__(256, 2) void gemm_kernel(const float* __restrict__ A,
                                                      const float* __restrict__ Bm,
                                                      const float* __restrict__ rn,
                                                      float* __restrict__ C) {
    constexpr int BK = 64;
    __shared__ __align__(16) short lAs[128 * BK];
    __shared__ __align__(16) short lBs[128 * BK];
    int bid = blockIdx.x;
    int nb  = (bid & 7) * 128 + (bid >> 3);
    int tm  = nb & 7;
    int tn  = nb >> 3;
    int m0 = tm * 128, n0 = tn * 128;
    int t = threadIdx.x;
    int lane = t & 63, w = t >> 6;
    int wr = (w >> 1) * 64, wc = (w & 1) * 64;
    f32x4 acc[4][4] = {};
    float4 ra[4][2], rb[4][2];
    float  sc[4];
    int    srow[4], sgrp[4];
    #pragma unroll
    for (int i = 0; i < 4; ++i) {
        int li = t + i * 256;
        srow[i] = li >> 3;
        sgrp[i] = li & 7;
        sc[i]   = rn[m0 + srow[i]];
    }
    auto load_tiles = [&](int kt) {
        int k0 = kt * BK;
        #pragma unroll
        for (int i = 0; i < 4; ++i) {
            const float4* pa = reinterpret_cast<const float4*>(
                A + (size_t)(m0 + srow[i]) * D_K + k0 + sgrp[i] * 8);
            ra[i][0] = pa[0]; ra[i][1] = pa[1];
            const float4* pb = reinterpret_cast<const float4*>(
                Bm + (size_t)(n0 + srow[i]) * D_K + k0 + sgrp[i] * 8);
            rb[i][0] = pb[0]; rb[i][1] = pb[1];
        }
    };
    auto write_tiles = [&]() {
        #pragma unroll
        for (int i = 0; i < 4; ++i) {
            int row = srow[i];
            int slotw = sgrp[i] ^ (row & 7);
            float s = sc[i];
            bf16x8 va, vb;
            va[0] = (short)f2bf(ra[i][0].x * s); va[1] = (short)f2bf(ra[i][0].y * s);
            va[2] = (short)f2bf(ra[i][0].z * s); va[3] = (short)f2bf(ra[i][0].w * s);
            va[4] = (short)f2bf(ra[i][1].x * s); va[5] = (short)f2bf(ra[i][1].y * s);
            va[6] = (short)f2bf(ra[i][1].z * s); va[7] = (short)f2bf(ra[i][1].w * s);
            vb[0] = (short)f2bf(rb[i][0].x); vb[1] = (short)f2bf(rb[i][0].y);
            vb[2] = (short)f2bf(rb[i][0].z); vb[3] = (short)f2bf(rb[i][0].w);
            vb[4] = (short)f2bf(rb[i][1].x); vb[5] = (short)f2bf(rb[i][1].y);
            vb[6] = (short)f2bf(rb[i][1].z); vb[7] = (short)f2bf(rb[i][1].w);
            *reinterpret_cast<bf16x8*>(&lAs[row * BK + slotw * 8]) = va;
            *reinterpret_cast<bf16x8*>(&lBs[row * BK + slotw * 8]) = vb;
        }
    };
    auto compute = [&]() {
        #pragma unroll
        for (int ks = 0; ks < 2; ++ks) {
            bf16x8 af[4], bfr[4];
            #pragma unroll
            for (int f = 0; f < 4; ++f) {
                int arow = wr + f * 16 + (lane & 15);
                int aslot = (ks * 4 + (lane >> 4)) ^ (arow & 7);
                af[f] = *reinterpret_cast<const bf16x8*>(&lAs[arow * BK + aslot * 8]);
                int brow = wc + f * 16 + (lane & 15);
                int bslot = (ks * 4 + (lane >> 4)) ^ (brow & 7);
                bfr[f] = *reinterpret_cast<const bf16x8*>(&lBs[brow * BK + bslot * 8]);
            }
            #pragma unroll
            for (int m = 0; m < 4; ++m)
                #pragma unroll
                for (int n = 0; n < 4; ++n)
                    acc[m][n] = __builtin_amdgcn_mfma_f32_16x16x32_bf16(
                        af[m], bfr[n], acc[m][n], 0, 0, 0);
        }
    };
    load_tiles(0);
    write_tiles();
    for (int kt = 1; kt < D_K / BK; ++kt) {
        __syncthreads();
        load_tiles(kt);
        compute();
        __syncthreads();
        write_tiles();
    }
    __syncthreads();
    compute();
    #pragma unroll
    for (int m = 0; m < 4; ++m) {
        int r = m0 + wr + m * 16 + (lane >> 4) * 4;
        #pragma unroll
        for (int j = 0; j < 4; ++j) {
            float* cp = C + (size_t)(r + j) * N_N + n0 + wc + (lane & 15);
            #pragma unroll
            for (int n = 0; n < 4; ++n)
                cp[n * 16] = acc[m][n][j] * TEMP_INV;
        }
    }
}

extern "C" void kernel_launch(void* const* d_in, const int* in_sizes, int n_in,
                              void* d_out, int out_size, void* d_ws, size_t ws_size,
                              hipStream_t stream) {
    const float* inputs   = (const float*)d_in[0];
    // d_in[1] = targets (unused by the forward output)
    const float* features = (const float*)d_in[2];
    float* out = (float*)d_out;

    const size_t needA = (size_t)M_M * D_K * 2;           // 4 MiB
    const size_t needB = (size_t)N_N * D_K * 2;           // 64 MiB
    if (ws_size >= needA + needB) {
        unsigned short* Abf = (unsigned short*)d_ws;
        unsigned short* Bbf = Abf + (size_t)M_M * D_K;
        prep_kernel<<<M_M + 2048, 256, 0, stream>>>(inputs, features, Abf, Bbf);
        gemm8_kernel<<<(M_M / 256) * (N_N / 256), 512, 0, stream>>>(Abf, Bbf, out);
    } else {
        float* rn = (float*)d_ws;   // 1024 floats
        rnorm_kernel<<<M_M, 256, 0, stream>>>(inputs, rn);
        gemm_kernel<<<(M_M / 128) * (N_N / 128), 256, 0, stream>>>(inputs, features, rn, out);
    }
}

// Round 10
// 103.836 us; speedup vs baseline: 1.1208x; 1.1208x over previous
//
#include <hip/hip_runtime.h>
#include <hip/hip_bf16.h>

// C[1024,16384] = l2norm_rows(inputs[1024,2048]) @ features[16384,2048]^T / 0.05
// Round 10: R8 pipeline + chunked counted lgkmcnt inside each GEMM phase
// (bfr reads first, then af; MFMA in 4-chunks under lgkmcnt 3/2/1/0).
// Stage/barrier/vmcnt ledger byte-identical to the verified R5/R8 kernel.

typedef short bf16x8 __attribute__((ext_vector_type(8)));
typedef float f32x4  __attribute__((ext_vector_type(4)));

#define D_K   2048
#define N_N   16384
#define M_M   1024
#define TEMP_INV 20.0f

__device__ __forceinline__ unsigned short f2bf(float f) {
    unsigned u = __builtin_bit_cast(unsigned, f);
    u += 0x7FFFu + ((u >> 16) & 1u);   // round-to-nearest-even (finite data)
    return (unsigned short)(u >> 16);
}

#define GLOAD16(g, l) __builtin_amdgcn_global_load_lds(                        \
    (const __attribute__((address_space(1))) unsigned int*)(g),                \
    (__attribute__((address_space(3))) unsigned int*)(l), 16, 0, 0)

// ---------------- pass 1: prep = anorm (blocks 0..1023) + bconv (rest) ----
__global__ __launch_bounds__(256) void prep_kernel(const float* __restrict__ x,
                                                   const float* __restrict__ B,
                                                   unsigned short* __restrict__ abf,
                                                   unsigned short* __restrict__ bbf) {
    int t = threadIdx.x;
    if (blockIdx.x < M_M) {
        int row = blockIdx.x;
        const float4* xr = reinterpret_cast<const float4*>(x + (size_t)row * D_K);
        float4 a = xr[t * 2];
        float4 b = xr[t * 2 + 1];
        float s = a.x*a.x + a.y*a.y + a.z*a.z + a.w*a.w
                + b.x*b.x + b.y*b.y + b.z*b.z + b.w*b.w;
        #pragma unroll
        for (int off = 32; off > 0; off >>= 1) s += __shfl_down(s, off);
        __shared__ float ps[4];
        __shared__ float sbc;
        if ((t & 63) == 0) ps[t >> 6] = s;
        __syncthreads();
        if (t == 0) {
            float tot = ps[0] + ps[1] + ps[2] + ps[3];
            sbc = 1.0f / fmaxf(sqrtf(tot), 1e-12f);
        }
        __syncthreads();
        float rs = sbc;
        bf16x8 v;
        v[0] = (short)f2bf(a.x * rs); v[1] = (short)f2bf(a.y * rs);
        v[2] = (short)f2bf(a.z * rs); v[3] = (short)f2bf(a.w * rs);
        v[4] = (short)f2bf(b.x * rs); v[5] = (short)f2bf(b.y * rs);
        v[6] = (short)f2bf(b.z * rs); v[7] = (short)f2bf(b.w * rs);
        *reinterpret_cast<bf16x8*>(abf + (size_t)row * D_K + t * 8) = v;
    } else {
        const size_t nv = (size_t)N_N * D_K / 8;
        size_t stride = (size_t)(gridDim.x - M_M) * blockDim.x;
        for (size_t v = (size_t)(blockIdx.x - M_M) * blockDim.x + t; v < nv; v += stride) {
            const float4* p = reinterpret_cast<const float4*>(B) + v * 2;
            float4 a = p[0], b = p[1];
            bf16x8 o;
            o[0] = (short)f2bf(a.x); o[1] = (short)f2bf(a.y);
            o[2] = (short)f2bf(a.z); o[3] = (short)f2bf(a.w);
            o[4] = (short)f2bf(b.x); o[5] = (short)f2bf(b.y);
            o[6] = (short)f2bf(b.z); o[7] = (short)f2bf(b.w);
            reinterpret_cast<bf16x8*>(bbf)[v] = o;
        }
    }
}

// ---------------- pass 2: 256x256 8-phase GEMM, chunked lgkm waits --------
// Structure/ledger identical to the R5/R8-verified kernel; only the intra-
// phase wait discipline changes: reads ordered bfr[0..3] then af[0..3];
// MFMA split into 4 chunks of 4 under lgkmcnt(3/2/1/0). Compiler's own
// dependency waitcnts guarantee correctness; asm waits shape the schedule.
__global__ __launch_bounds__(512, 2) void gemm8_kernel(const unsigned short* __restrict__ Abf,
                                                       const unsigned short* __restrict__ Bbf,
                                                       float* __restrict__ C) {
    __shared__ __align__(16) unsigned short lds[65536];   // 128 KiB

    // 256 wgs = 4 Mtiles x 64 Ntiles; bijective XCD swizzle (256 % 8 == 0).
    int bid = blockIdx.x;
    int wg  = (bid & 7) * 32 + (bid >> 3);
    int tm  = wg & 3, tn = wg >> 2;
    int m_blk = tm * 256, n_blk = tn * 256;

    int t = threadIdx.x, lane = t & 63, w = t >> 6;
    int wm = w >> 2, wn = w & 3;                     // 2 x 4 wave grid

    // ds_read lane constants: slot = chunk ^ ((row>>1)&3)
    int l15  = lane & 15;
    int slot = ((lane >> 4) ^ ((l15 >> 1) & 3)) * 16;     // byte slot offset
    int aoff = (wm * 128 + l15) * 64 + slot;              // A region byte off
    int boff = (wn * 64  + l15) * 64 + slot;              // B region byte off

    // stage source pointers (pre-swizzled global chunk per rule #21)
    const unsigned short* gA[2];
    const unsigned short* gB[2];
    int sdst[2];
    #pragma unroll
    for (int pass = 0; pass < 2; ++pass) {
        int r = pass * 128 + (t >> 2);
        int csrc = (t & 3) ^ ((r >> 1) & 3);
        gA[pass] = Abf + (size_t)(m_blk + r) * D_K + csrc * 8;
        gB[pass] = Bbf + (size_t)(n_blk + r) * D_K + csrc * 8;
        sdst[pass] = pass * 8192 + w * 1024;   // wave-uniform LDS dest base
    }

    // stage one half-tile: region (mat, s) of K-tile kt into buffer b
    auto stage = [&](int mat, int s, int b, int ktile) {
        int kt = ktile < 32 ? ktile : 31;              // tail clamp (dead regions)
        int koff = kt * 64 + s * 32;
        int ldsb = b * 65536 + mat * 32768 + s * 16384;
        GLOAD16((mat ? gB[0] : gA[0]) + koff, (char*)lds + ldsb + sdst[0]);
        GLOAD16((mat ? gB[1] : gA[1]) + koff, (char*)lds + ldsb + sdst[1]);
    };

    f32x4 acc[8][4] = {};
    bf16x8 bfr[4];                                     // persists across phase pairs

#define LGKM(n) asm volatile("s_waitcnt lgkmcnt(" #n ")" ::: "memory");        \
                __builtin_amdgcn_sched_barrier(0)

#define PHASE(b, mh, s, LOADB, stMat, stS, stB, stKt, VM)                      \
    {                                                                          \
        if (LOADB) {                                                           \
            _Pragma("unroll")                                                  \
            for (int n = 0; n < 4; ++n)                                        \
                bfr[n] = *reinterpret_cast<const bf16x8*>(                     \
                    (char*)lds + (b) * 65536 + 32768 + (s) * 16384 + boff +    \
                    n * 1024);                                                 \
        }                                                                      \
        bf16x8 af[4];                                                          \
        _Pragma("unroll")                                                      \
        for (int f = 0; f < 4; ++f)                                            \
            af[f] = *reinterpret_cast<const bf16x8*>(                          \
                (char*)lds + (b) * 65536 + (s) * 16384 + aoff +                \
                ((mh) * 64 + f * 16) * 64);                                    \
        stage(stMat, stS, stB, stKt);                                          \
        asm volatile("s_barrier" ::: "memory");                                \
        __builtin_amdgcn_s_setprio(1);                                         \
        LGKM(3);                                                               \
        _Pragma("unroll")                                                      \
        for (int n = 0; n < 4; ++n)                                            \
            acc[(mh) * 4 + 0][n] = __builtin_amdgcn_mfma_f32_16x16x32_bf16(    \
                af[0], bfr[n], acc[(mh) * 4 + 0][n], 0, 0, 0);                 \
        LGKM(2);                                                               \
        _Pragma("unroll")                                                      \
        for (int n = 0; n < 4; ++n)                                            \
            acc[(mh) * 4 + 1][n] = __builtin_amdgcn_mfma_f32_16x16x32_bf16(    \
                af[1], bfr[n], acc[(mh) * 4 + 1][n], 0, 0, 0);                 \
        LGKM(1);                                                               \
        _Pragma("unroll")                                                      \
        for (int n = 0; n < 4; ++n)                                            \
            acc[(mh) * 4 + 2][n] = __builtin_amdgcn_mfma_f32_16x16x32_bf16(    \
                af[2], bfr[n], acc[(mh) * 4 + 2][n], 0, 0, 0);                 \
        LGKM(0);                                                               \
        _Pragma("unroll")                                                      \
        for (int n = 0; n < 4; ++n)                                            \
            acc[(mh) * 4 + 3][n] = __builtin_amdgcn_mfma_f32_16x16x32_bf16(    \
                af[3], bfr[n], acc[(mh) * 4 + 3][n], 0, 0, 0);                 \
        __builtin_amdgcn_s_setprio(0);                                         \
        if (VM) asm volatile("s_waitcnt vmcnt(8)" ::: "memory");               \
        asm volatile("s_barrier" ::: "memory");                                \
    }

    // prologue: K0 full + K1 k0-halves; vmcnt(8) -> oldest 4 ops (K0 k0) landed
    stage(0, 0, 0, 0);   // A-k0(0) -> buf0
    stage(1, 0, 0, 0);   // B-k0(0)
    stage(0, 1, 0, 0);   // A-k1(0)
    stage(1, 1, 0, 0);   // B-k1(0)
    stage(0, 0, 1, 1);   // A-k0(1) -> buf1
    stage(1, 0, 1, 1);   // B-k0(1)
    asm volatile("s_waitcnt vmcnt(8)" ::: "memory");
    asm volatile("s_barrier" ::: "memory");

    for (int u = 0; u < 16; ++u) {
        int t1 = 2 * u + 1;
        // K-tile 2u (buf0)
        PHASE(0, 0, 0, true,  0, 1, 1, t1,     false)   // stage A-k1(t1)->buf1
        PHASE(0, 1, 0, false, 1, 1, 1, t1,     true )   // stage B-k1(t1)->buf1
        PHASE(0, 0, 1, true,  0, 0, 0, t1 + 1, false)   // stage A-k0(t1+1)->buf0
        PHASE(0, 1, 1, false, 1, 0, 0, t1 + 1, true )   // stage B-k0(t1+1)->buf0
        // K-tile 2u+1 (buf1)
        PHASE(1, 0, 0, true,  0, 1, 0, t1 + 1, false)   // stage A-k1(t1+1)->buf0
        PHASE(1, 1, 0, false, 1, 1, 0, t1 + 1, true )   // stage B-k1(t1+1)->buf0
        PHASE(1, 0, 1, true,  0, 0, 1, t1 + 2, false)   // stage A-k0(t1+2)->buf1
        PHASE(1, 1, 1, false, 1, 0, 1, t1 + 2, true )   // stage B-k0(t1+2)->buf1
    }
#undef PHASE
#undef LGKM

    // epilogue: C/D layout col=lane&15, row=(lane>>4)*4+j [m89-verified]
    #pragma unroll
    for (int f = 0; f < 8; ++f) {
        int r = m_blk + wm * 128 + (f >> 2) * 64 + (f & 3) * 16 + (lane >> 4) * 4;
        #pragma unroll
        for (int j = 0; j < 4; ++j) {
            float* cp = C + (size_t)(r + j) * N_N + n_blk + wn * 64 + (lane & 15);
            #pragma unroll
            for (int n = 0; n < 4; ++n)
                cp[n * 16] = acc[f][n][j] * TEMP_INV;
        }
    }
}

// ================= fallback (round-1 fused fp32-staged kernel) ============
__global__ __launch_bounds__(256) void rnorm_kernel(const float* __restrict__ x,
                                                    float* __restrict__ rn) {
    int row = blockIdx.x;
    const float4* xr = reinterpret_cast<const float4*>(x + (size_t)row * D_K);
    int t = threadIdx.x;
    float4 a = xr[t];
    float4 b = xr[t + 256];
    float s = a.x*a.x + a.y*a.y + a.z*a.z + a.w*a.w
            + b.x*b.x + b.y*b.y + b.z*b.z + b.w*b.w;
    #pragma unroll
    for (int off = 32; off > 0; off >>= 1) s += __shfl_down(s, off);
    __shared__ float ps[4];
    int wave = t >> 6, lane = t & 63;
    if (lane == 0) ps[wave] = s;
    __syncthreads();
    if (t == 0) {
        float tot = ps[0] + ps[1] + ps[2] + ps[3];
        rn[row] = 1.0f / fmaxf(sqrtf(tot), 1e-12f);
    }
}

__global__ __launch_bounds__(256, 2) void gemm_kernel(const float* __restrict__ A,
                                                      const float* __restrict__ Bm,
                                                      const float* __restrict__ rn,
                                                      float* __restrict__ C) {
    constexpr int BK = 64;
    __shared__ __align__(16) short lAs[128 * BK];
    __shared__ __align__(16) short lBs[128 * BK];
    int bid = blockIdx.x;
    int nb  = (bid & 7) * 128 + (bid >> 3);
    int tm  = nb & 7;
    int tn  = nb >> 3;
    int m0 = tm * 128, n0 = tn * 128;
    int t = threadIdx.x;
    int lane = t & 63, w = t >> 6;
    int wr = (w >> 1) * 64, wc = (w & 1) * 64;
    f32x4 acc[4][4] = {};
    float4 ra[4][2], rb[4][2];
    float  sc[4];
    int    srow[4], sgrp[4];
    #pragma unroll
    for (int i = 0; i < 4; ++i) {
        int li = t + i * 256;
        srow[i] = li >> 3;
        sgrp[i] = li & 7;
        sc[i]   = rn[m0 + srow[i]];
    }
    auto load_tiles = [&](int kt) {
        int k0 = kt * BK;
        #pragma unroll
        for (int i = 0; i < 4; ++i) {
            const float4* pa = reinterpret_cast<const float4*>(
                A + (size_t)(m0 + srow[i]) * D_K + k0 + sgrp[i] * 8);
            ra[i][0] = pa[0]; ra[i][1] = pa[1];
            const float4* pb = reinterpret_cast<const float4*>(
                Bm + (size_t)(n0 + srow[i]) * D_K + k0 + sgrp[i] * 8);
            rb[i][0] = pb[0]; rb[i][1] = pb[1];
        }
    };
    auto write_tiles = [&]() {
        #pragma unroll
        for (int i = 0; i < 4; ++i) {
            int row = srow[i];
            int slotw = sgrp[i] ^ (row & 7);
            float s = sc[i];
            bf16x8 va, vb;
            va[0] = (short)f2bf(ra[i][0].x * s); va[1] = (short)f2bf(ra[i][0].y * s);
            va[2] = (short)f2bf(ra[i][0].z * s); va[3] = (short)f2bf(ra[i][0].w * s);
            va[4] = (short)f2bf(ra[i][1].x * s); va[5] = (short)f2bf(ra[i][1].y * s);
            va[6] = (short)f2bf(ra[i][1].z * s); va[7] = (short)f2bf(ra[i][1].w * s);
            vb[0] = (short)f2bf(rb[i][0].x); vb[1] = (short)f2bf(rb[i][0].y);
            vb[2] = (short)f2bf(rb[i][0].z); vb[3] = (short)f2bf(rb[i][0].w);
            vb[4] = (short)f2bf(rb[i][1].x); vb[5] = (short)f2bf(rb[i][1].y);
            vb[6] = (short)f2bf(rb[i][1].z); vb[7] = (short)f2bf(rb[i][1].w);
            *reinterpret_cast<bf16x8*>(&lAs[row * BK + slotw * 8]) = va;
            *reinterpret_cast<bf16x8*>(&lBs[row * BK + slotw * 8]) = vb;
        }
    };
    auto compute = [&]() {
        #pragma unroll
        for (int ks = 0; ks < 2; ++ks) {
            bf16x8 af[4], bfr[4];
            #pragma unroll
            for (int f = 0; f < 4; ++f) {
                int arow = wr + f * 16 + (lane & 15);
                int aslot = (ks * 4 + (lane >> 4)) ^ (arow & 7);
                af[f] = *reinterpret_cast<const bf16x8*>(&lAs[arow * BK + aslot * 8]);
                int brow = wc + f * 16 + (lane & 15);
                int bslot = (ks * 4 + (lane >> 4)) ^ (brow & 7);
                bfr[f] = *reinterpret_cast<const bf16x8*>(&lBs[brow * BK + bslot * 8]);
            }
            #pragma unroll
            for (int m = 0; m < 4; ++m)
                #pragma unroll
                for (int n = 0; n < 4; ++n)
                    acc[m][n] = __builtin_amdgcn_mfma_f32_16x16x32_bf16(
                        af[m], bfr[n], acc[m][n], 0, 0, 0);
        }
    };
    load_tiles(0);
    write_tiles();
    for (int kt = 1; kt < D_K / BK; ++kt) {
        __syncthreads();
        load_tiles(kt);
        compute();
        __syncthreads();
        write_tiles();
    }
    __syncthreads();
    compute();
    #pragma unroll
    for (int m = 0; m < 4; ++m) {
        int r = m0 + wr + m * 16 + (lane >> 4) * 4;
        #pragma unroll
        for (int j = 0; j < 4; ++j) {
            float* cp = C + (size_t)(r + j) * N_N + n0 + wc + (lane & 15);
            #pragma unroll
            for (int n = 0; n < 4; ++n)
                cp[n * 16] = acc[m][n][j] * TEMP_INV;
        }
    }
}

extern "C" void kernel_launch(void* const* d_in, const int* in_sizes, int n_in,
                              void* d_out, int out_size, void* d_ws, size_t ws_size,
                              hipStream_t stream) {
    const float* inputs   = (const float*)d_in[0];
    // d_in[1] = targets (unused by the forward output)
    const float* features = (const float*)d_in[2];
    float* out = (float*)d_out;

    const size_t needA = (size_t)M_M * D_K * 2;           // 4 MiB
    const size_t needB = (size_t)N_N * D_K * 2;           // 64 MiB
    if (ws_size >= needA + needB) {
        unsigned short* Abf = (unsigned short*)d_ws;
        unsigned short* Bbf = Abf + (size_t)M_M * D_K;
        prep_kernel<<<M_M + 2048, 256, 0, stream>>>(inputs, features, Abf, Bbf);
        gemm8_kernel<<<(M_M / 256) * (N_N / 256), 512, 0, stream>>>(Abf, Bbf, out);
    } else {
        float* rn = (float*)d_ws;   // 1024 floats
        rnorm_kernel<<<M_M, 256, 0, stream>>>(inputs, rn);
        gemm_kernel<<<(M_M / 128) * (N_N / 128), 256, 0, stream>>>(inputs, features, rn, out);
    }
}